// Round 2
// 362.102 us; speedup vs baseline: 1.0788x; 1.0788x over previous
//
#include <hip/hip_runtime.h>
#include <hip/hip_bf16.h>

// Problem constants
#define BB 16
#define TT 1024
#define DD 256
#define NE 512
#define BT 16384   // BB*TT

typedef unsigned short ushort_t;
typedef __attribute__((ext_vector_type(8))) short bf16x8;
typedef __attribute__((ext_vector_type(4))) float f32x4;

#define AS_GLOBAL __attribute__((address_space(1)))
#define AS_SHARED __attribute__((address_space(3)))

static __device__ __forceinline__ ushort_t f2bf(float f) {
    union { float f; unsigned u; } x; x.f = f;
    unsigned r = x.u + 0x7fffu + ((x.u >> 16) & 1u);   // RNE
    return (ushort_t)(r >> 16);
}

// ---------------------------------------------------------------------------
// Row-wise L2 normalize, cols == 256. Optional bf16 copy of the output.
// ---------------------------------------------------------------------------
__global__ __launch_bounds__(256) void l2norm_dual(const float* __restrict__ in,
                                                   float* __restrict__ out,
                                                   ushort_t* __restrict__ out_bf) {
    const int row = blockIdx.x;
    const long long base = (long long)row * DD;
    const int t = threadIdx.x;
    float v = in[base + t];
    float ss = v * v;
    #pragma unroll
    for (int off = 32; off > 0; off >>= 1) ss += __shfl_down(ss, off, 64);
    __shared__ float partial[4];
    const int wave = t >> 6, lane = t & 63;
    if (lane == 0) partial[wave] = ss;
    __syncthreads();
    __shared__ float s_inv;
    if (t == 0) {
        float tot = partial[0] + partial[1] + partial[2] + partial[3];
        s_inv = 1.0f / fmaxf(sqrtf(tot), 1e-12f);
    }
    __syncthreads();
    const float r = v * s_inv;
    out[base + t] = r;
    if (out_bf) out_bf[base + t] = f2bf(r);
}

// ---------------------------------------------------------------------------
// Transpose fp32 [rows, cols] -> bf16 [cols, rows]
// ---------------------------------------------------------------------------
__global__ void transpose_bf(const float* __restrict__ in, ushort_t* __restrict__ out,
                             int rows, int cols) {
    int idx = blockIdx.x * blockDim.x + threadIdx.x;
    if (idx < rows * cols) {
        int r = idx / cols, c = idx - r * cols;
        out[(long long)c * rows + r] = f2bf(in[idx]);
    }
}

// ---------------------------------------------------------------------------
// bf16 MFMA GEMM: C[M,N]fp32 = A[M,K]bf16 * B[N,K]bf16^T
// 128x128 tile, BK=32, 256 threads = 4 waves, each wave 64x64 (4x4 MFMA tiles).
// global -> LDS via global_load_lds width 16. M,N %128==0, K %32==0.
// ---------------------------------------------------------------------------
__global__ __launch_bounds__(256) void gemm_bf16_nt(const ushort_t* __restrict__ A,
                                                    const ushort_t* __restrict__ Bm,
                                                    float* __restrict__ C,
                                                    int M, int N, int K,
                                                    long long sA, long long sB, long long sC) {
    A  += sA * blockIdx.z;
    Bm += sB * blockIdx.z;
    C  += sC * blockIdx.z;
    const int bm = blockIdx.y * 128;
    const int bn = blockIdx.x * 128;

    __shared__ ushort_t As[128 * 32];   // [row][k], k contiguous (global_load_lds order)
    __shared__ ushort_t Bs[128 * 32];

    const int tid = threadIdx.x;
    const int wv = tid >> 6;            // wave 0..3
    const int ln = tid & 63;

    // staging lanes: 16 rows x 4 chunks of 8 bf16 per instruction
    const int srow   = ln >> 2;         // 0..15
    const int schunk = (ln & 3) * 8;    // 0,8,16,24

    // MFMA fragment coords
    const int wm = (wv >> 1) * 64;      // wave m-offset in tile
    const int wn = (wv & 1) * 64;      // wave n-offset
    const int fr = ln & 15;             // row within 16-tile
    const int fq = (ln >> 4) * 8;       // k-offset within 32

    f32x4 acc[4][4] = {};

    for (int k0 = 0; k0 < K; k0 += 32) {
        #pragma unroll
        for (int t = 0; t < 2; ++t) {
            const int ra = wv * 32 + t * 16;   // local row base (wave-uniform)
            const ushort_t* ga = A + (long long)(bm + ra + srow) * K + k0 + schunk;
            __builtin_amdgcn_global_load_lds((const AS_GLOBAL void*)ga,
                                             (AS_SHARED void*)&As[ra * 32], 16, 0, 0);
            const ushort_t* gb = Bm + (long long)(bn + ra + srow) * K + k0 + schunk;
            __builtin_amdgcn_global_load_lds((const AS_GLOBAL void*)gb,
                                             (AS_SHARED void*)&Bs[ra * 32], 16, 0, 0);
        }
        __syncthreads();

        bf16x8 af[4], bfr[4];
        #pragma unroll
        for (int i = 0; i < 4; ++i)
            af[i] = *(const bf16x8*)&As[(wm + i * 16 + fr) * 32 + fq];
        #pragma unroll
        for (int j = 0; j < 4; ++j)
            bfr[j] = *(const bf16x8*)&Bs[(wn + j * 16 + fr) * 32 + fq];
        #pragma unroll
        for (int i = 0; i < 4; ++i)
            #pragma unroll
            for (int j = 0; j < 4; ++j)
                acc[i][j] = __builtin_amdgcn_mfma_f32_16x16x32_bf16(af[i], bfr[j], acc[i][j], 0, 0, 0);
        __syncthreads();
    }

    // C/D layout: col = lane&15, row = (lane>>4)*4 + reg
    const int col  = ln & 15;
    const int qrow = (ln >> 4) * 4;
    #pragma unroll
    for (int i = 0; i < 4; ++i)
        #pragma unroll
        for (int j = 0; j < 4; ++j) {
            #pragma unroll
            for (int r = 0; r < 4; ++r)
                C[(long long)(bm + wm + i * 16 + qrow + r) * N + bn + wn + j * 16 + col] = acc[i][j][r];
        }
}

// ---------------------------------------------------------------------------
// Per row of score_ksh [BT, NE]: softmax weights (bf16) + fp64-refined argmax.
// S comes from the bf16 MFMA GEMM. The true argmax is guaranteed to lie within
// DELTA of the observed bf16 max: |bf16 dot - fp32 dot| <= 2*2^-8*sum|a||b|
// <= ~0.0078 per score => chain bound 0.0156 < DELTA.
// Candidates are re-scored in FP64 FROM THE RAW INPUTS (query norm cancels
// across candidates), so the selected index is the true argmax to ~1e-16 —
// strictly more accurate than any fp32 reference accumulation order.
// ---------------------------------------------------------------------------
__global__ __launch_bounds__(256) void softmax_argmax(const float* __restrict__ S,
                                                      const float* __restrict__ ks_raw,
                                                      const float* __restrict__ keys_raw,
                                                      float* __restrict__ idx_out,
                                                      ushort_t* __restrict__ W) {
    const int row = blockIdx.x;
    const long long base = (long long)row * NE;
    const int t = threadIdx.x;
    const float v0 = S[base + t];
    const float v1 = S[base + t + 256];

    // 1) block max of bf16-GEMM scores (value only; index from fp64 refine)
    float bv = fmaxf(v0, v1);
    #pragma unroll
    for (int off = 32; off > 0; off >>= 1) bv = fmaxf(bv, __shfl_down(bv, off, 64));
    __shared__ float pv[4];
    const int wave = t >> 6, lane = t & 63;
    if (lane == 0) pv[wave] = bv;
    __syncthreads();
    __shared__ float s_max;
    if (t == 0) s_max = fmaxf(fmaxf(pv[0], pv[1]), fmaxf(pv[2], pv[3]));
    __syncthreads();
    const float m = s_max;

    // 2) candidate collection within the bf16 error margin
    __shared__ int cand[128];
    __shared__ int ncand;
    if (t == 0) ncand = 0;
    __syncthreads();
    const float DELTA = 0.02f;   // worst-case chain bound 0.0156, plus slack
    if (v0 >= m - DELTA) { int p = atomicAdd(&ncand, 1); if (p < 128) cand[p] = t; }
    if (v1 >= m - DELTA) { int p = atomicAdd(&ncand, 1); if (p < 128) cand[p] = t + 256; }
    __syncthreads();
    const int nc = min(ncand, 128);

    // 3) refine in fp64 from raw inputs: wave w handles candidates w, w+4, ...
    //    score ordering: dot(ks_raw, keys_raw[c]) / ||keys_raw[c]||
    //    (the query norm is a common positive factor — it cancels)
    __shared__ double wbv[4];
    __shared__ int    wbi[4];
    {
        double best = -1e300; int besti = 0x7fffffff;
        const float* arow = ks_raw + (long long)row * DD;
        const double a0 = (double)arow[lane];
        const double a1 = (double)arow[lane + 64];
        const double a2 = (double)arow[lane + 128];
        const double a3 = (double)arow[lane + 192];
        for (int k = wave; k < nc; k += 4) {
            const int c = cand[k];
            const float* krow = keys_raw + (long long)c * DD;
            const double b0 = (double)krow[lane];
            const double b1 = (double)krow[lane + 64];
            const double b2 = (double)krow[lane + 128];
            const double b3 = (double)krow[lane + 192];
            double dp = a0 * b0 + a1 * b1 + a2 * b2 + a3 * b3;
            double nb = b0 * b0 + b1 * b1 + b2 * b2 + b3 * b3;
            #pragma unroll
            for (int off = 32; off > 0; off >>= 1) {
                dp += __shfl_down(dp, off, 64);
                nb += __shfl_down(nb, off, 64);
            }
            dp = __shfl(dp, 0, 64);
            nb = __shfl(nb, 0, 64);
            const double d = dp / sqrt(nb);
            if (d > best || (d == best && c < besti)) { best = d; besti = c; }
        }
        if (lane == 0) { wbv[wave] = best; wbi[wave] = besti; }
    }
    __syncthreads();
    if (t == 0) {
        double best = wbv[0]; int besti = wbi[0];
        #pragma unroll
        for (int k = 1; k < 4; ++k)
            if (wbv[k] > best || (wbv[k] == best && wbi[k] < besti)) { best = wbv[k]; besti = wbi[k]; }
        idx_out[row] = (float)besti;
    }

    // 4) softmax (shift by m; exact shift value is irrelevant numerically)
    const float e0 = expf(v0 - m);
    const float e1 = expf(v1 - m);
    float ssum = e0 + e1;
    #pragma unroll
    for (int off = 32; off > 0; off >>= 1) ssum += __shfl_down(ssum, off, 64);
    __shared__ float ps[4];
    if (lane == 0) ps[wave] = ssum;
    __syncthreads();
    __shared__ float s_sum;
    if (t == 0) s_sum = ps[0] + ps[1] + ps[2] + ps[3];
    __syncthreads();
    const float inv = 1.0f / s_sum;
    W[base + t]       = f2bf(e0 * inv);
    W[base + t + 256] = f2bf(e1 * inv);
}

// ---------------------------------------------------------------------------
// Normalize raw vparams_w rows -> vpw fp32 + bf16; gather vp_norm[idx] -> vph.
// ---------------------------------------------------------------------------
__global__ __launch_bounds__(256) void vpw_finish(const float* __restrict__ raw,
                                                  const float* __restrict__ idxf,
                                                  const float* __restrict__ vp_norm,
                                                  float* __restrict__ vpw,
                                                  ushort_t* __restrict__ vpw_bf,
                                                  float* __restrict__ vph) {
    const int row = blockIdx.x;
    const long long base = (long long)row * DD;
    const int t = threadIdx.x;
    const float v = raw[base + t];
    float ss = v * v;
    #pragma unroll
    for (int off = 32; off > 0; off >>= 1) ss += __shfl_down(ss, off, 64);
    __shared__ float partial[4];
    const int wave = t >> 6, lane = t & 63;
    if (lane == 0) partial[wave] = ss;
    __syncthreads();
    __shared__ float s_inv;
    if (t == 0) {
        float tot = partial[0] + partial[1] + partial[2] + partial[3];
        s_inv = 1.0f / fmaxf(sqrtf(tot), 1e-12f);
    }
    __syncthreads();
    const float r = v * s_inv;
    vpw[base + t] = r;
    vpw_bf[base + t] = f2bf(r);
    const int idx = (int)idxf[row];
    vph[base + t] = vp_norm[(long long)idx * DD + t];
}

// ---------------------------------------------------------------------------
extern "C" void kernel_launch(void* const* d_in, const int* in_sizes, int n_in,
                              void* d_out, int out_size, void* d_ws, size_t ws_size,
                              hipStream_t stream) {
    const float* key_soft = (const float*)d_in[0];   // [16,1024,256]
    const float* keys     = (const float*)d_in[1];   // [512,256]
    const float* vparams  = (const float*)d_in[2];   // [512,256]
    float* out = (float*)d_out;

    // Output layout (flat, return order)
    const long long off0 = 0;                               // encoding_indices [16384]
    const long long off1 = off0 + BT;                       // vparams_w  [16384,256]
    const long long off2 = off1 + (long long)BT * DD;       // vparams_hard
    const long long off3 = off2 + (long long)BT * DD;       // score_vpss [16,1024,1024]
    const long long off4 = off3 + (long long)BB * TT * TT;  // score_vpsh [16384,512]
    const long long off5 = off4 + (long long)BT * NE;       // score_kss [16,1024,1024]
    const long long off6 = off5 + (long long)BB * TT * TT;  // score_ksh [16384,512]

    float* o_idx  = out + off0;
    float* o_vpw  = out + off1;
    float* o_vph  = out + off2;
    float* o_vpss = out + off3;
    float* o_vpsh = out + off4;
    float* o_kss  = out + off5;
    float* o_ksh  = out + off6;

    // ws scratch (~10 MB, well under the known-good 17.7 MB footprint)
    float*    keys_n    = (float*)d_ws;                           // [512,256] fp32
    float*    vp_n      = keys_n + (long long)NE * DD;            // [512,256] fp32
    ushort_t* vp_n_bf   = (ushort_t*)(vp_n + (long long)NE * DD); // [512,256] bf16
    ushort_t* vpnT_bf   = vp_n_bf + (long long)NE * DD;           // [256,512] bf16
    ushort_t* vpw_bf    = vpnT_bf + (long long)DD * NE;           // [16384,256] bf16
    ushort_t* keys_n_bf = vpw_bf + (long long)BT * DD;            // [512,256] bf16

    // Borrowed d_out regions (each consumed before its region is overwritten):
    float*    ksn     = o_kss;                                  // [16384,256] fp32 (dead after step 2; o_kss written at step 5)
    ushort_t* ksn_bf  = (ushort_t*)o_vpsh;                      // [16384,256] bf16 (dead after kss gemm; o_vpsh written last)
    float*    raw_scr = o_vpss;                                 // [16384,256] fp32 raw vparams_w
    ushort_t* w_bf    = (ushort_t*)(o_vpss + (long long)BT * DD); // [16384,512] bf16 softmax weights, +16MB into vpss region

    // 1) normalizations (+ bf16 copies)
    l2norm_dual<<<BT, 256, 0, stream>>>(key_soft, ksn, ksn_bf);
    l2norm_dual<<<NE, 256, 0, stream>>>(keys, keys_n, keys_n_bf);
    l2norm_dual<<<NE, 256, 0, stream>>>(vparams, vp_n, vp_n_bf);
    transpose_bf<<<(NE * DD + 255) / 256, 256, 0, stream>>>(vp_n, vpnT_bf, NE, DD);

    // 2) score_ksh = ksn @ keys_n^T via bf16 MFMA (argmax is fp64-refined later)
    gemm_bf16_nt<<<dim3(NE / 128, BT / 128, 1), 256, 0, stream>>>(
        ksn_bf, keys_n_bf, o_ksh, BT, NE, DD, 0, 0, 0);

    // 3) softmax -> w_bf; argmax with margin-based fp64 refinement on raw inputs
    softmax_argmax<<<BT, 256, 0, stream>>>(o_ksh, key_soft, keys, o_idx, w_bf);

    // 4) raw vparams_w = w @ vp_n   (A=w_bf [BT,512], B=vpnT_bf [256,512])
    gemm_bf16_nt<<<dim3(DD / 128, BT / 128, 1), 256, 0, stream>>>(
        w_bf, vpnT_bf, raw_scr, BT, DD, NE, 0, 0, 0);

    // 5) score_kss = ksn_bf @ ksn_bf^T per batch (overwrites ksn fp32 — dead)
    gemm_bf16_nt<<<dim3(TT / 128, TT / 128, BB), 256, 0, stream>>>(
        ksn_bf, ksn_bf, o_kss, TT, TT, DD,
        (long long)TT * DD, (long long)TT * DD, (long long)TT * TT);

    // 6) normalize + hard gather (+ vpw bf16 into ws)
    vpw_finish<<<BT, 256, 0, stream>>>(raw_scr, o_idx, vp_n, o_vpw, vpw_bf, o_vph);

    // 7) score_vpss = vpw @ vpw^T per batch (overwrites raw_scr + w_bf — both dead)
    gemm_bf16_nt<<<dim3(TT / 128, TT / 128, BB), 256, 0, stream>>>(
        vpw_bf, vpw_bf, o_vpss, TT, TT, DD,
        (long long)TT * DD, (long long)TT * DD, (long long)TT * TT);

    // 8) score_vpsh = vpw @ vp_n^T (overwrites ksn_bf — dead)
    gemm_bf16_nt<<<dim3(NE / 128, BT / 128, 1), 256, 0, stream>>>(
        vpw_bf, vp_n_bf, o_vpsh, BT, NE, DD, 0, 0, 0);
}

// Round 3
// 325.648 us; speedup vs baseline: 1.1995x; 1.1119x over previous
//
#include <hip/hip_runtime.h>
#include <hip/hip_bf16.h>

// Problem constants
#define BB 16
#define TT 1024
#define DD 256
#define NE 512
#define BT 16384   // BB*TT

typedef unsigned short ushort_t;
typedef __attribute__((ext_vector_type(8))) short bf16x8;
typedef __attribute__((ext_vector_type(4))) float f32x4;

#define AS_GLOBAL __attribute__((address_space(1)))
#define AS_SHARED __attribute__((address_space(3)))

static __device__ __forceinline__ ushort_t f2bf(float f) {
    union { float f; unsigned u; } x; x.f = f;
    unsigned r = x.u + 0x7fffu + ((x.u >> 16) & 1u);   // RNE
    return (ushort_t)(r >> 16);
}

// ---------------------------------------------------------------------------
// prep_all: one dispatch for all input normalizations.
//  bid < 4096 : 4 rows of key_soft per block, one wave per row (no barriers).
//               writes ksn_bf only (fp32 ksn is dead: argmax refine uses raw).
//  else       : b2 = bid-4096 in [0,1024): b2<512 -> keys row (keys_n_bf only);
//               else vparams row -> vp_n fp32 + vp_n_bf + vpnT_bf scatter.
// ---------------------------------------------------------------------------
__global__ __launch_bounds__(256) void prep_all(const float* __restrict__ ks,
                                                const float* __restrict__ keys,
                                                const float* __restrict__ vparams,
                                                ushort_t* __restrict__ ksn_bf,
                                                ushort_t* __restrict__ keys_n_bf,
                                                float* __restrict__ vp_n,
                                                ushort_t* __restrict__ vp_n_bf,
                                                ushort_t* __restrict__ vpnT_bf) {
    const int bid = blockIdx.x;
    const int t = threadIdx.x;
    if (bid < 4096) {
        const int row  = bid * 4 + (t >> 6);
        const int lane = t & 63;
        const float4 v = *(const float4*)(ks + (long long)row * DD + lane * 4);
        float ss = v.x * v.x + v.y * v.y + v.z * v.z + v.w * v.w;
        #pragma unroll
        for (int off = 32; off > 0; off >>= 1) ss += __shfl_down(ss, off, 64);
        ss = __shfl(ss, 0, 64);
        const float inv = 1.0f / fmaxf(sqrtf(ss), 1e-12f);
        unsigned long long p =
              (unsigned long long)f2bf(v.x * inv)
            | ((unsigned long long)f2bf(v.y * inv) << 16)
            | ((unsigned long long)f2bf(v.z * inv) << 32)
            | ((unsigned long long)f2bf(v.w * inv) << 48);
        *(unsigned long long*)(ksn_bf + (long long)row * DD + lane * 4) = p;
    } else {
        const int b2 = bid - 4096;
        const bool is_keys = (b2 < NE);
        const int rr = is_keys ? b2 : b2 - NE;
        const float* src = (is_keys ? keys : vparams) + (long long)rr * DD;
        const float v = src[t];
        float ss = v * v;
        #pragma unroll
        for (int off = 32; off > 0; off >>= 1) ss += __shfl_down(ss, off, 64);
        __shared__ float partial[4];
        const int wave = t >> 6, lane = t & 63;
        if (lane == 0) partial[wave] = ss;
        __syncthreads();
        __shared__ float s_inv;
        if (t == 0) {
            float tot = partial[0] + partial[1] + partial[2] + partial[3];
            s_inv = 1.0f / fmaxf(sqrtf(tot), 1e-12f);
        }
        __syncthreads();
        const float r = v * s_inv;
        const ushort_t b = f2bf(r);
        if (is_keys) {
            keys_n_bf[(long long)rr * DD + t] = b;
        } else {
            vp_n[(long long)rr * DD + t] = r;
            vp_n_bf[(long long)rr * DD + t] = b;
            vpnT_bf[(long long)t * NE + rr] = b;   // [DD][NE] transpose scatter
        }
    }
}

// ---------------------------------------------------------------------------
// mega_gemm: TWO bf16 NT-GEMM problem sets in one dispatch (identical tile
// geometry: 128x128 tiles, K=256, lda=ldb=256).
//   bid < 1024 : batched set — 16 batches of [TT,DD]x[TT,DD]^T -> [TT,TT]
//   else       : flat set    — [BT,DD] x [NE,DD]^T -> [BT,NE]   (512 tiles)
// 256 threads = 4 waves, each 64x64 (4x4 of 16x16x32 MFMA).
// ---------------------------------------------------------------------------
__global__ __launch_bounds__(256) void mega_gemm(const ushort_t* __restrict__ Ab,
                                                 const ushort_t* __restrict__ Bb,
                                                 float* __restrict__ Cb,
                                                 const ushort_t* __restrict__ Af,
                                                 const ushort_t* __restrict__ Bf,
                                                 float* __restrict__ Cf) {
    const int bid = blockIdx.x;
    const ushort_t *A, *Bm;
    float* C;
    int bm, bn, ldc;
    if (bid < 1024) {
        const int z = bid >> 6, t6 = bid & 63;
        A  = Ab + (long long)z * TT * DD;
        Bm = Bb + (long long)z * TT * DD;
        C  = Cb + (long long)z * TT * TT;
        bm = (t6 >> 3) * 128; bn = (t6 & 7) * 128; ldc = TT;
    } else {
        const int f = bid - 1024;
        A = Af; Bm = Bf; C = Cf;
        bm = (f >> 2) * 128; bn = (f & 3) * 128; ldc = NE;
    }

    __shared__ ushort_t As[128 * 32];   // [row][k], k contiguous
    __shared__ ushort_t Bs[128 * 32];

    const int tid = threadIdx.x;
    const int wv = tid >> 6;
    const int ln = tid & 63;
    const int srow   = ln >> 2;         // 0..15
    const int schunk = (ln & 3) * 8;    // 0,8,16,24
    const int wm = (wv >> 1) * 64;
    const int wn = (wv & 1) * 64;
    const int fr = ln & 15;
    const int fq = (ln >> 4) * 8;

    f32x4 acc[4][4] = {};

    for (int k0 = 0; k0 < DD; k0 += 32) {
        #pragma unroll
        for (int t = 0; t < 2; ++t) {
            const int ra = wv * 32 + t * 16;
            const ushort_t* ga = A + (long long)(bm + ra + srow) * DD + k0 + schunk;
            __builtin_amdgcn_global_load_lds((const AS_GLOBAL void*)ga,
                                             (AS_SHARED void*)&As[ra * 32], 16, 0, 0);
            const ushort_t* gb = Bm + (long long)(bn + ra + srow) * DD + k0 + schunk;
            __builtin_amdgcn_global_load_lds((const AS_GLOBAL void*)gb,
                                             (AS_SHARED void*)&Bs[ra * 32], 16, 0, 0);
        }
        __syncthreads();

        bf16x8 af[4], bfr[4];
        #pragma unroll
        for (int i = 0; i < 4; ++i)
            af[i] = *(const bf16x8*)&As[(wm + i * 16 + fr) * 32 + fq];
        #pragma unroll
        for (int j = 0; j < 4; ++j)
            bfr[j] = *(const bf16x8*)&Bs[(wn + j * 16 + fr) * 32 + fq];
        #pragma unroll
        for (int i = 0; i < 4; ++i)
            #pragma unroll
            for (int j = 0; j < 4; ++j)
                acc[i][j] = __builtin_amdgcn_mfma_f32_16x16x32_bf16(af[i], bfr[j], acc[i][j], 0, 0, 0);
        __syncthreads();
    }

    const int col  = ln & 15;
    const int qrow = (ln >> 4) * 4;
    #pragma unroll
    for (int i = 0; i < 4; ++i)
        #pragma unroll
        for (int j = 0; j < 4; ++j)
            #pragma unroll
            for (int r = 0; r < 4; ++r)
                C[(long long)(bm + wm + i * 16 + qrow + r) * ldc + bn + wn + j * 16 + col] = acc[i][j][r];
}

// ---------------------------------------------------------------------------
// Per row of score_ksh [BT, NE]: softmax weights (bf16) + fp64-refined argmax.
// (verified in R2 — unchanged)
// ---------------------------------------------------------------------------
__global__ __launch_bounds__(256) void softmax_argmax(const float* __restrict__ S,
                                                      const float* __restrict__ ks_raw,
                                                      const float* __restrict__ keys_raw,
                                                      float* __restrict__ idx_out,
                                                      ushort_t* __restrict__ W) {
    const int row = blockIdx.x;
    const long long base = (long long)row * NE;
    const int t = threadIdx.x;
    const float v0 = S[base + t];
    const float v1 = S[base + t + 256];

    float bv = fmaxf(v0, v1);
    #pragma unroll
    for (int off = 32; off > 0; off >>= 1) bv = fmaxf(bv, __shfl_down(bv, off, 64));
    __shared__ float pv[4];
    const int wave = t >> 6, lane = t & 63;
    if (lane == 0) pv[wave] = bv;
    __syncthreads();
    __shared__ float s_max;
    if (t == 0) s_max = fmaxf(fmaxf(pv[0], pv[1]), fmaxf(pv[2], pv[3]));
    __syncthreads();
    const float m = s_max;

    __shared__ int cand[128];
    __shared__ int ncand;
    if (t == 0) ncand = 0;
    __syncthreads();
    const float DELTA = 0.02f;   // worst-case bf16 chain bound 0.0156 + slack
    if (v0 >= m - DELTA) { int p = atomicAdd(&ncand, 1); if (p < 128) cand[p] = t; }
    if (v1 >= m - DELTA) { int p = atomicAdd(&ncand, 1); if (p < 128) cand[p] = t + 256; }
    __syncthreads();
    const int nc = min(ncand, 128);

    __shared__ double wbv[4];
    __shared__ int    wbi[4];
    {
        double best = -1e300; int besti = 0x7fffffff;
        const float* arow = ks_raw + (long long)row * DD;
        const double a0 = (double)arow[lane];
        const double a1 = (double)arow[lane + 64];
        const double a2 = (double)arow[lane + 128];
        const double a3 = (double)arow[lane + 192];
        for (int k = wave; k < nc; k += 4) {
            const int c = cand[k];
            const float* krow = keys_raw + (long long)c * DD;
            const double b0 = (double)krow[lane];
            const double b1 = (double)krow[lane + 64];
            const double b2 = (double)krow[lane + 128];
            const double b3 = (double)krow[lane + 192];
            double dp = a0 * b0 + a1 * b1 + a2 * b2 + a3 * b3;
            double nb = b0 * b0 + b1 * b1 + b2 * b2 + b3 * b3;
            #pragma unroll
            for (int off = 32; off > 0; off >>= 1) {
                dp += __shfl_down(dp, off, 64);
                nb += __shfl_down(nb, off, 64);
            }
            dp = __shfl(dp, 0, 64);
            nb = __shfl(nb, 0, 64);
            const double d = dp / sqrt(nb);
            if (d > best || (d == best && c < besti)) { best = d; besti = c; }
        }
        if (lane == 0) { wbv[wave] = best; wbi[wave] = besti; }
    }
    __syncthreads();
    if (t == 0) {
        double best = wbv[0]; int besti = wbi[0];
        #pragma unroll
        for (int k = 1; k < 4; ++k)
            if (wbv[k] > best || (wbv[k] == best && wbi[k] < besti)) { best = wbv[k]; besti = wbi[k]; }
        idx_out[row] = (float)besti;
    }

    const float e0 = expf(v0 - m);
    const float e1 = expf(v1 - m);
    float ssum = e0 + e1;
    #pragma unroll
    for (int off = 32; off > 0; off >>= 1) ssum += __shfl_down(ssum, off, 64);
    __shared__ float ps[4];
    if (lane == 0) ps[wave] = ssum;
    __syncthreads();
    __shared__ float s_sum;
    if (t == 0) s_sum = ps[0] + ps[1] + ps[2] + ps[3];
    __syncthreads();
    const float inv = 1.0f / s_sum;
    W[base + t]       = f2bf(e0 * inv);
    W[base + t + 256] = f2bf(e1 * inv);
}

// ---------------------------------------------------------------------------
// gemm_vpw_norm: raw = W[BT,NE] @ vpnT[DD,NE]^T with the row-l2-normalize,
// bf16 conversion, and hard-gather fused into the epilogue.
// Tile: 64 rows x 256 cols (full row width), 4 waves side by side (each 64x64),
// K = NE = 512.  Grid: BT/64 = 256 workgroups.
// Eliminates the raw_scr round-trip (32 MB) and the vpw_finish dispatch.
// ---------------------------------------------------------------------------
__global__ __launch_bounds__(256) void gemm_vpw_norm(const ushort_t* __restrict__ Aw,
                                                     const ushort_t* __restrict__ BvT,
                                                     const float* __restrict__ idxf,
                                                     const float* __restrict__ vp_n,
                                                     float* __restrict__ vpw,
                                                     ushort_t* __restrict__ vpw_bf,
                                                     float* __restrict__ vph) {
    const int bm = blockIdx.x * 64;

    __shared__ ushort_t As[64 * 32];
    __shared__ ushort_t Bs[256 * 32];

    const int tid = threadIdx.x;
    const int wv = tid >> 6;
    const int ln = tid & 63;
    const int srow   = ln >> 2;
    const int schunk = (ln & 3) * 8;
    const int wn = wv * 64;             // waves tile columns
    const int fr = ln & 15;
    const int fq = (ln >> 4) * 8;

    f32x4 acc[4][4] = {};

    for (int k0 = 0; k0 < NE; k0 += 32) {
        // 20 stage instructions (4 for As, 16 for Bs), 5 per wave
        #pragma unroll
        for (int s = 0; s < 5; ++s) {
            const int g = wv * 5 + s;   // 0..19, wave-uniform
            if (g < 4) {
                const ushort_t* ga = Aw + (long long)(bm + g * 16 + srow) * NE + k0 + schunk;
                __builtin_amdgcn_global_load_lds((const AS_GLOBAL void*)ga,
                                                 (AS_SHARED void*)&As[(g * 16) * 32], 16, 0, 0);
            } else {
                const int rb = (g - 4) * 16;
                const ushort_t* gb = BvT + (long long)(rb + srow) * NE + k0 + schunk;
                __builtin_amdgcn_global_load_lds((const AS_GLOBAL void*)gb,
                                                 (AS_SHARED void*)&Bs[rb * 32], 16, 0, 0);
            }
        }
        __syncthreads();

        bf16x8 af[4], bfr[4];
        #pragma unroll
        for (int i = 0; i < 4; ++i)
            af[i] = *(const bf16x8*)&As[(i * 16 + fr) * 32 + fq];
        #pragma unroll
        for (int j = 0; j < 4; ++j)
            bfr[j] = *(const bf16x8*)&Bs[(wn + j * 16 + fr) * 32 + fq];
        #pragma unroll
        for (int i = 0; i < 4; ++i)
            #pragma unroll
            for (int j = 0; j < 4; ++j)
                acc[i][j] = __builtin_amdgcn_mfma_f32_16x16x32_bf16(af[i], bfr[j], acc[i][j], 0, 0, 0);
        __syncthreads();
    }

    // ---- fused epilogue: row l2-norm across the 4 waves ----
    __shared__ float sq[64][4];
    __shared__ float inv_s[64];
    __shared__ int   sidx[64];
    const int qrow = (ln >> 4) * 4;
    #pragma unroll
    for (int i = 0; i < 4; ++i) {
        #pragma unroll
        for (int r = 0; r < 4; ++r) {
            float s = 0.0f;
            #pragma unroll
            for (int j = 0; j < 4; ++j) { const float a = acc[i][j][r]; s += a * a; }
            // reduce over the 16-lane column group (xor bits 0..3 keep group)
            #pragma unroll
            for (int msk = 1; msk < 16; msk <<= 1) s += __shfl_xor(s, msk, 64);
            if ((ln & 15) == 0) sq[i * 16 + qrow + r][wv] = s;
        }
    }
    if (tid < 64) sidx[tid] = (int)idxf[bm + tid];
    __syncthreads();
    if (tid < 64) {
        const float tot = sq[tid][0] + sq[tid][1] + sq[tid][2] + sq[tid][3];
        inv_s[tid] = 1.0f / fmaxf(sqrtf(tot), 1e-12f);
    }
    __syncthreads();

    const int col = ln & 15;
    #pragma unroll
    for (int i = 0; i < 4; ++i)
        #pragma unroll
        for (int r = 0; r < 4; ++r) {
            const int row = i * 16 + qrow + r;
            const float iv = inv_s[row];
            #pragma unroll
            for (int j = 0; j < 4; ++j) {
                const float v = acc[i][j][r] * iv;
                const long long o = (long long)(bm + row) * DD + wn + j * 16 + col;
                vpw[o] = v;
                vpw_bf[o] = f2bf(v);
            }
        }

    // hard gather: vph[row] = vp_n[idx[row]]  (thread t = column t, coalesced)
    for (int k = 0; k < 64; ++k) {
        const int grow = bm + k;
        vph[(long long)grow * DD + tid] = vp_n[(long long)sidx[k] * DD + tid];
    }
}

// ---------------------------------------------------------------------------
extern "C" void kernel_launch(void* const* d_in, const int* in_sizes, int n_in,
                              void* d_out, int out_size, void* d_ws, size_t ws_size,
                              hipStream_t stream) {
    const float* key_soft = (const float*)d_in[0];   // [16,1024,256]
    const float* keys     = (const float*)d_in[1];   // [512,256]
    const float* vparams  = (const float*)d_in[2];   // [512,256]
    float* out = (float*)d_out;

    // Output layout (flat, return order)
    const long long off0 = 0;                               // encoding_indices [16384]
    const long long off1 = off0 + BT;                       // vparams_w  [16384,256]
    const long long off2 = off1 + (long long)BT * DD;       // vparams_hard
    const long long off3 = off2 + (long long)BT * DD;       // score_vpss [16,1024,1024]
    const long long off4 = off3 + (long long)BB * TT * TT;  // score_vpsh [16384,512]
    const long long off5 = off4 + (long long)BT * NE;       // score_kss [16,1024,1024]
    const long long off6 = off5 + (long long)BB * TT * TT;  // score_ksh [16384,512]

    float* o_idx  = out + off0;
    float* o_vpw  = out + off1;
    float* o_vph  = out + off2;
    float* o_vpss = out + off3;
    float* o_vpsh = out + off4;
    float* o_kss  = out + off5;
    float* o_ksh  = out + off6;

    // ws scratch (~9 MB)
    float*    vp_n      = (float*)d_ws;                           // [512,256] fp32
    ushort_t* vp_n_bf   = (ushort_t*)(vp_n + (long long)NE * DD); // [512,256] bf16
    ushort_t* vpnT_bf   = vp_n_bf + (long long)NE * DD;           // [256,512] bf16
    ushort_t* vpw_bf    = vpnT_bf + (long long)DD * NE;           // [16384,256] bf16
    ushort_t* keys_n_bf = vpw_bf + (long long)BT * DD;            // [512,256] bf16

    // Borrowed d_out regions (each consumed before its region is overwritten):
    ushort_t* ksn_bf = (ushort_t*)o_vpsh;                         // [16384,256] bf16 (dead after mega1; o_vpsh written in mega2)
    ushort_t* w_bf   = (ushort_t*)(o_vpss + (long long)BT * DD);  // [16384,512] bf16 weights, +16MB into vpss region (dead after gemm_vpw_norm; o_vpss written in mega2)

    // 1) all normalizations in one dispatch
    prep_all<<<4096 + 2 * NE, 256, 0, stream>>>(
        key_soft, keys, vparams, ksn_bf, keys_n_bf, vp_n, vp_n_bf, vpnT_bf);

    // 2) kss (16 batches, 1024 tiles) + ksh (512 tiles) in one dispatch
    mega_gemm<<<1536, 256, 0, stream>>>(
        ksn_bf, ksn_bf, o_kss, ksn_bf, keys_n_bf, o_ksh);

    // 3) softmax -> w_bf; argmax with margin-based fp64 refinement on raw inputs
    softmax_argmax<<<BT, 256, 0, stream>>>(o_ksh, key_soft, keys, o_idx, w_bf);

    // 4) vparams_w gemm with fused normalize + bf16 + hard gather
    gemm_vpw_norm<<<BT / 64, 256, 0, stream>>>(
        w_bf, vpnT_bf, o_idx, vp_n, o_vpw, vpw_bf, o_vph);

    // 5) vpss (16 batches) + vpsh in one dispatch
    mega_gemm<<<1536, 256, 0, stream>>>(
        vpw_bf, vpw_bf, o_vpss, vpw_bf, vp_n_bf, o_vpsh);
}

// Round 4
// 311.992 us; speedup vs baseline: 1.2520x; 1.0438x over previous
//
#include <hip/hip_runtime.h>
#include <hip/hip_bf16.h>

// Problem constants
#define BB 16
#define TT 1024
#define DD 256
#define NE 512
#define BT 16384   // BB*TT

typedef unsigned short ushort_t;
typedef unsigned long long ull_t;
typedef __attribute__((ext_vector_type(8))) short bf16x8;
typedef __attribute__((ext_vector_type(4))) float f32x4;

#define AS_GLOBAL __attribute__((address_space(1)))
#define AS_SHARED __attribute__((address_space(3)))

static __device__ __forceinline__ ushort_t f2bf(float f) {
    union { float f; unsigned u; } x; x.f = f;
    unsigned r = x.u + 0x7fffu + ((x.u >> 16) & 1u);   // RNE
    return (ushort_t)(r >> 16);
}

// ---------------------------------------------------------------------------
// prep_all: one dispatch for all input normalizations (verified R3).
// ---------------------------------------------------------------------------
__global__ __launch_bounds__(256) void prep_all(const float* __restrict__ ks,
                                                const float* __restrict__ keys,
                                                const float* __restrict__ vparams,
                                                ushort_t* __restrict__ ksn_bf,
                                                ushort_t* __restrict__ keys_n_bf,
                                                float* __restrict__ vp_n,
                                                ushort_t* __restrict__ vp_n_bf,
                                                ushort_t* __restrict__ vpnT_bf) {
    const int bid = blockIdx.x;
    const int t = threadIdx.x;
    if (bid < 4096) {
        const int row  = bid * 4 + (t >> 6);
        const int lane = t & 63;
        const float4 v = *(const float4*)(ks + (long long)row * DD + lane * 4);
        float ss = v.x * v.x + v.y * v.y + v.z * v.z + v.w * v.w;
        #pragma unroll
        for (int off = 32; off > 0; off >>= 1) ss += __shfl_down(ss, off, 64);
        ss = __shfl(ss, 0, 64);
        const float inv = 1.0f / fmaxf(sqrtf(ss), 1e-12f);
        ull_t p =
              (ull_t)f2bf(v.x * inv)
            | ((ull_t)f2bf(v.y * inv) << 16)
            | ((ull_t)f2bf(v.z * inv) << 32)
            | ((ull_t)f2bf(v.w * inv) << 48);
        *(ull_t*)(ksn_bf + (long long)row * DD + lane * 4) = p;
    } else {
        const int b2 = bid - 4096;
        const bool is_keys = (b2 < NE);
        const int rr = is_keys ? b2 : b2 - NE;
        const float* src = (is_keys ? keys : vparams) + (long long)rr * DD;
        const float v = src[t];
        float ss = v * v;
        #pragma unroll
        for (int off = 32; off > 0; off >>= 1) ss += __shfl_down(ss, off, 64);
        __shared__ float partial[4];
        const int wave = t >> 6, lane = t & 63;
        if (lane == 0) partial[wave] = ss;
        __syncthreads();
        __shared__ float s_inv;
        if (t == 0) {
            float tot = partial[0] + partial[1] + partial[2] + partial[3];
            s_inv = 1.0f / fmaxf(sqrtf(tot), 1e-12f);
        }
        __syncthreads();
        const float r = v * s_inv;
        const ushort_t b = f2bf(r);
        if (is_keys) {
            keys_n_bf[(long long)rr * DD + t] = b;
        } else {
            vp_n[(long long)rr * DD + t] = r;
            vp_n_bf[(long long)rr * DD + t] = b;
            vpnT_bf[(long long)t * NE + rr] = b;   // [DD][NE] transpose scatter
        }
    }
}

// ---------------------------------------------------------------------------
// mega_gemm: symmetric batched set + flat set, one dispatch.
//   bid < 576 : batched SYMMETRIC — 16 batches of X[TT,DD] X^T, upper-triangle
//               tiles only (36 of 64); off-diagonal tiles also write the
//               transposed block (float4 stores).
//   else      : flat — [BT,DD] x [NE,DD]^T -> [BT,NE] (512 tiles).
// 2-phase prefetch: stage K-step k+1 into the other LDS buffer BEFORE
// computing step k; one barrier per step (T3-minimum).
// ---------------------------------------------------------------------------
__global__ __launch_bounds__(256) void mega_gemm(const ushort_t* __restrict__ Ab,
                                                 float* __restrict__ Cb,
                                                 const ushort_t* __restrict__ Af,
                                                 const ushort_t* __restrict__ Bf,
                                                 float* __restrict__ Cf) {
    const int bid = blockIdx.x;
    const ushort_t *A, *Bm;
    float* C;
    int bm, bn, ldc;
    bool sym;
    if (bid < 576) {
        const int z = bid / 36;
        int tt = bid - z * 36;
        int i = 0;
        while (tt >= 8 - i) { tt -= 8 - i; ++i; }
        const int j = i + tt;
        A  = Ab + (long long)z * TT * DD;
        Bm = A;
        C  = Cb + (long long)z * TT * TT;
        bm = i * 128; bn = j * 128; ldc = TT;
        sym = (i != j);
    } else {
        const int f = bid - 576;
        A = Af; Bm = Bf; C = Cf;
        bm = (f >> 2) * 128; bn = (f & 3) * 128; ldc = NE;
        sym = false;
    }

    __shared__ ushort_t As[2][128 * 32];
    __shared__ ushort_t Bs[2][128 * 32];

    const int tid = threadIdx.x;
    const int wv = tid >> 6;
    const int ln = tid & 63;
    const int srow   = ln >> 2;         // 0..15
    const int schunk = (ln & 3) * 8;    // 0,8,16,24
    const int wm = (wv >> 1) * 64;
    const int wn = (wv & 1) * 64;
    const int fr = ln & 15;
    const int fq = (ln >> 4) * 8;

    f32x4 acc[4][4] = {};

#define MG_STAGE(buf, kk)                                                          \
    {                                                                              \
        _Pragma("unroll")                                                          \
        for (int s = 0; s < 2; ++s) {                                              \
            const int ra = wv * 32 + s * 16;                                       \
            const ushort_t* ga = A + (long long)(bm + ra + srow) * DD + (kk) + schunk; \
            __builtin_amdgcn_global_load_lds((const AS_GLOBAL void*)ga,            \
                (AS_SHARED void*)&As[buf][ra * 32], 16, 0, 0);                     \
            const ushort_t* gb = Bm + (long long)(bn + ra + srow) * DD + (kk) + schunk; \
            __builtin_amdgcn_global_load_lds((const AS_GLOBAL void*)gb,            \
                (AS_SHARED void*)&Bs[buf][ra * 32], 16, 0, 0);                     \
        }                                                                          \
    }

#define MG_COMPUTE(buf)                                                            \
    {                                                                              \
        bf16x8 af[4], bfr[4];                                                      \
        _Pragma("unroll")                                                          \
        for (int i = 0; i < 4; ++i)                                                \
            af[i] = *(const bf16x8*)&As[buf][(wm + i * 16 + fr) * 32 + fq];        \
        _Pragma("unroll")                                                          \
        for (int j = 0; j < 4; ++j)                                                \
            bfr[j] = *(const bf16x8*)&Bs[buf][(wn + j * 16 + fr) * 32 + fq];       \
        _Pragma("unroll")                                                          \
        for (int i = 0; i < 4; ++i)                                                \
            _Pragma("unroll")                                                      \
            for (int j = 0; j < 4; ++j)                                            \
                acc[i][j] = __builtin_amdgcn_mfma_f32_16x16x32_bf16(af[i], bfr[j], acc[i][j], 0, 0, 0); \
    }

    MG_STAGE(0, 0);
    __syncthreads();
    int cur = 0;
    #pragma unroll
    for (int k0 = 32; k0 < DD; k0 += 32) {
        MG_STAGE(cur ^ 1, k0);
        MG_COMPUTE(cur);
        __syncthreads();
        cur ^= 1;
    }
    MG_COMPUTE(cur);

    const int col  = ln & 15;
    const int qrow = (ln >> 4) * 4;
    #pragma unroll
    for (int i = 0; i < 4; ++i)
        #pragma unroll
        for (int j = 0; j < 4; ++j)
            #pragma unroll
            for (int r = 0; r < 4; ++r)
                C[(long long)(bm + wm + i * 16 + qrow + r) * ldc + bn + wn + j * 16 + col] = acc[i][j][r];

    if (sym) {
        // transposed block: C[bn+.., bm+..] = acc^T; per lane a float4 of
        // 4 consecutive columns (qrow..qrow+3) in row bn+wn+j*16+col.
        #pragma unroll
        for (int i = 0; i < 4; ++i)
            #pragma unroll
            for (int j = 0; j < 4; ++j) {
                float4 v = make_float4(acc[i][j][0], acc[i][j][1], acc[i][j][2], acc[i][j][3]);
                *(float4*)&C[(long long)(bn + wn + j * 16 + col) * ldc + bm + wm + i * 16 + qrow] = v;
            }
    }
#undef MG_STAGE
#undef MG_COMPUTE
}

// ---------------------------------------------------------------------------
// softmax_argmax: one WAVE per row (4 rows/block), barrier-free, no LDS.
// Softmax weights (bf16) + fp64-refined argmax from raw inputs (query norm
// cancels; refine bound: bf16 GEMM error <= 0.0156 < DELTA=0.02).
// ---------------------------------------------------------------------------
__global__ __launch_bounds__(256) void softmax_argmax(const float* __restrict__ S,
                                                      const float* __restrict__ ks_raw,
                                                      const float* __restrict__ keys_raw,
                                                      float* __restrict__ idx_out,
                                                      ushort_t* __restrict__ W) {
    const int row  = blockIdx.x * 4 + (threadIdx.x >> 6);
    const int lane = threadIdx.x & 63;
    const long long base = (long long)row * NE;

    const float4 va = *(const float4*)(S + base + lane * 4);
    const float4 vb = *(const float4*)(S + base + 256 + lane * 4);

    // wave max
    float m8 = fmaxf(fmaxf(fmaxf(va.x, va.y), fmaxf(va.z, va.w)),
                     fmaxf(fmaxf(vb.x, vb.y), fmaxf(vb.z, vb.w)));
    #pragma unroll
    for (int off = 32; off > 0; off >>= 1) m8 = fmaxf(m8, __shfl_xor(m8, off, 64));
    const float m = m8;

    // candidate collection (bf16 error margin) via ballot — no LDS, no atomics
    const float thr = m - 0.02f;
    unsigned mask = (va.x >= thr ? 1u : 0u) | (va.y >= thr ? 2u : 0u)
                  | (va.z >= thr ? 4u : 0u) | (va.w >= thr ? 8u : 0u)
                  | (vb.x >= thr ? 16u : 0u) | (vb.y >= thr ? 32u : 0u)
                  | (vb.z >= thr ? 64u : 0u) | (vb.w >= thr ? 128u : 0u);
    ull_t bal = __ballot(mask != 0);

    // fp64 refine from raw inputs: whole wave per candidate (uniform loop)
    const float4 af = *(const float4*)(ks_raw + (long long)row * DD + lane * 4);
    double best = -1e300; int besti = 0x7fffffff;
    while (bal) {
        const int src = (int)__builtin_ctzll(bal);
        bal &= bal - 1;
        unsigned sm = (unsigned)__shfl((int)mask, src, 64);
        while (sm) {
            const int slot = __builtin_ctz(sm);
            sm &= sm - 1;
            const int c = (slot < 4) ? (src * 4 + slot) : (256 + src * 4 + slot - 4);
            const float4 bf4 = *(const float4*)(keys_raw + (long long)c * DD + lane * 4);
            double dp = (double)af.x * (double)bf4.x + (double)af.y * (double)bf4.y
                      + (double)af.z * (double)bf4.z + (double)af.w * (double)bf4.w;
            double nb = (double)bf4.x * (double)bf4.x + (double)bf4.y * (double)bf4.y
                      + (double)bf4.z * (double)bf4.z + (double)bf4.w * (double)bf4.w;
            #pragma unroll
            for (int off = 32; off > 0; off >>= 1) {
                dp += __shfl_xor(dp, off, 64);
                nb += __shfl_xor(nb, off, 64);
            }
            const double d = dp / sqrt(nb);
            if (d > best || (d == best && c < besti)) { best = d; besti = c; }
        }
    }
    if (lane == 0) idx_out[row] = (float)besti;

    // softmax
    const float e0 = expf(va.x - m), e1 = expf(va.y - m), e2 = expf(va.z - m), e3 = expf(va.w - m);
    const float e4 = expf(vb.x - m), e5 = expf(vb.y - m), e6 = expf(vb.z - m), e7 = expf(vb.w - m);
    float ssum = ((e0 + e1) + (e2 + e3)) + ((e4 + e5) + (e6 + e7));
    #pragma unroll
    for (int off = 32; off > 0; off >>= 1) ssum += __shfl_xor(ssum, off, 64);
    const float inv = 1.0f / ssum;
    ull_t p0 = (ull_t)f2bf(e0 * inv) | ((ull_t)f2bf(e1 * inv) << 16)
             | ((ull_t)f2bf(e2 * inv) << 32) | ((ull_t)f2bf(e3 * inv) << 48);
    ull_t p1 = (ull_t)f2bf(e4 * inv) | ((ull_t)f2bf(e5 * inv) << 16)
             | ((ull_t)f2bf(e6 * inv) << 32) | ((ull_t)f2bf(e7 * inv) << 48);
    *(ull_t*)(W + base + lane * 4) = p0;
    *(ull_t*)(W + base + 256 + lane * 4) = p1;
}

// ---------------------------------------------------------------------------
// gemm_vpw_norm: raw = W[BT,NE] @ vpnT[DD,NE]^T with fused l2-normalize,
// bf16 conversion, hard-gather. 64x256 tile, K=512, 2-phase prefetch.
// ---------------------------------------------------------------------------
__global__ __launch_bounds__(256) void gemm_vpw_norm(const ushort_t* __restrict__ Aw,
                                                     const ushort_t* __restrict__ BvT,
                                                     const float* __restrict__ idxf,
                                                     const float* __restrict__ vp_n,
                                                     float* __restrict__ vpw,
                                                     ushort_t* __restrict__ vpw_bf,
                                                     float* __restrict__ vph) {
    const int bm = blockIdx.x * 64;

    __shared__ ushort_t As[2][64 * 32];
    __shared__ ushort_t Bs[2][256 * 32];

    const int tid = threadIdx.x;
    const int wv = tid >> 6;
    const int ln = tid & 63;
    const int srow   = ln >> 2;
    const int schunk = (ln & 3) * 8;
    const int wn = wv * 64;             // waves tile columns
    const int fr = ln & 15;
    const int fq = (ln >> 4) * 8;

    f32x4 acc[4][4] = {};

#define VW_STAGE(buf, kk)                                                          \
    {                                                                              \
        _Pragma("unroll")                                                          \
        for (int s = 0; s < 5; ++s) {                                              \
            const int g = wv * 5 + s;                                              \
            if (g < 4) {                                                           \
                const ushort_t* ga = Aw + (long long)(bm + g * 16 + srow) * NE + (kk) + schunk; \
                __builtin_amdgcn_global_load_lds((const AS_GLOBAL void*)ga,        \
                    (AS_SHARED void*)&As[buf][(g * 16) * 32], 16, 0, 0);           \
            } else {                                                               \
                const int rb = (g - 4) * 16;                                       \
                const ushort_t* gb = BvT + (long long)(rb + srow) * NE + (kk) + schunk; \
                __builtin_amdgcn_global_load_lds((const AS_GLOBAL void*)gb,        \
                    (AS_SHARED void*)&Bs[buf][rb * 32], 16, 0, 0);                 \
            }                                                                      \
        }                                                                          \
    }

#define VW_COMPUTE(buf)                                                            \
    {                                                                              \
        bf16x8 af[4], bfr[4];                                                      \
        _Pragma("unroll")                                                          \
        for (int i = 0; i < 4; ++i)                                                \
            af[i] = *(const bf16x8*)&As[buf][(i * 16 + fr) * 32 + fq];             \
        _Pragma("unroll")                                                          \
        for (int j = 0; j < 4; ++j)                                                \
            bfr[j] = *(const bf16x8*)&Bs[buf][(wn + j * 16 + fr) * 32 + fq];       \
        _Pragma("unroll")                                                          \
        for (int i = 0; i < 4; ++i)                                                \
            _Pragma("unroll")                                                      \
            for (int j = 0; j < 4; ++j)                                            \
                acc[i][j] = __builtin_amdgcn_mfma_f32_16x16x32_bf16(af[i], bfr[j], acc[i][j], 0, 0, 0); \
    }

    VW_STAGE(0, 0);
    __syncthreads();
    int cur = 0;
    for (int k0 = 32; k0 < NE; k0 += 32) {
        VW_STAGE(cur ^ 1, k0);
        VW_COMPUTE(cur);
        __syncthreads();
        cur ^= 1;
    }
    VW_COMPUTE(cur);

    // ---- fused epilogue: row l2-norm across the 4 waves ----
    __shared__ float sq[64][4];
    __shared__ float inv_s[64];
    __shared__ int   sidx[64];
    const int qrow = (ln >> 4) * 4;
    #pragma unroll
    for (int i = 0; i < 4; ++i) {
        #pragma unroll
        for (int r = 0; r < 4; ++r) {
            float s = 0.0f;
            #pragma unroll
            for (int j = 0; j < 4; ++j) { const float a = acc[i][j][r]; s += a * a; }
            #pragma unroll
            for (int msk = 1; msk < 16; msk <<= 1) s += __shfl_xor(s, msk, 64);
            if ((ln & 15) == 0) sq[i * 16 + qrow + r][wv] = s;
        }
    }
    if (tid < 64) sidx[tid] = (int)idxf[bm + tid];
    __syncthreads();
    if (tid < 64) {
        const float tot = sq[tid][0] + sq[tid][1] + sq[tid][2] + sq[tid][3];
        inv_s[tid] = 1.0f / fmaxf(sqrtf(tot), 1e-12f);
    }
    __syncthreads();

    const int col = ln & 15;
    #pragma unroll
    for (int i = 0; i < 4; ++i)
        #pragma unroll
        for (int r = 0; r < 4; ++r) {
            const int row = i * 16 + qrow + r;
            const float iv = inv_s[row];
            #pragma unroll
            for (int j = 0; j < 4; ++j) {
                const float v = acc[i][j][r] * iv;
                const long long o = (long long)(bm + row) * DD + wn + j * 16 + col;
                vpw[o] = v;
                vpw_bf[o] = f2bf(v);
            }
        }

    // hard gather: vph[row] = vp_n[idx[row]]  (thread t = column t, coalesced)
    for (int k = 0; k < 64; ++k) {
        const int grow = bm + k;
        vph[(long long)grow * DD + tid] = vp_n[(long long)sidx[k] * DD + tid];
    }
#undef VW_STAGE
#undef VW_COMPUTE
}

// ---------------------------------------------------------------------------
extern "C" void kernel_launch(void* const* d_in, const int* in_sizes, int n_in,
                              void* d_out, int out_size, void* d_ws, size_t ws_size,
                              hipStream_t stream) {
    const float* key_soft = (const float*)d_in[0];   // [16,1024,256]
    const float* keys     = (const float*)d_in[1];   // [512,256]
    const float* vparams  = (const float*)d_in[2];   // [512,256]
    float* out = (float*)d_out;

    // Output layout (flat, return order)
    const long long off0 = 0;                               // encoding_indices [16384]
    const long long off1 = off0 + BT;                       // vparams_w  [16384,256]
    const long long off2 = off1 + (long long)BT * DD;       // vparams_hard
    const long long off3 = off2 + (long long)BT * DD;       // score_vpss [16,1024,1024]
    const long long off4 = off3 + (long long)BB * TT * TT;  // score_vpsh [16384,512]
    const long long off5 = off4 + (long long)BT * NE;       // score_kss [16,1024,1024]
    const long long off6 = off5 + (long long)BB * TT * TT;  // score_ksh [16384,512]

    float* o_idx  = out + off0;
    float* o_vpw  = out + off1;
    float* o_vph  = out + off2;
    float* o_vpss = out + off3;
    float* o_vpsh = out + off4;
    float* o_kss  = out + off5;
    float* o_ksh  = out + off6;

    // ws scratch (~9 MB)
    float*    vp_n      = (float*)d_ws;                           // [512,256] fp32
    ushort_t* vp_n_bf   = (ushort_t*)(vp_n + (long long)NE * DD); // [512,256] bf16
    ushort_t* vpnT_bf   = vp_n_bf + (long long)NE * DD;           // [256,512] bf16
    ushort_t* vpw_bf    = vpnT_bf + (long long)DD * NE;           // [16384,256] bf16
    ushort_t* keys_n_bf = vpw_bf + (long long)BT * DD;            // [512,256] bf16

    // Borrowed d_out regions (each consumed before its region is overwritten):
    ushort_t* ksn_bf = (ushort_t*)o_vpsh;                         // [16384,256] bf16 (dead after mega1; o_vpsh written in mega2)
    ushort_t* w_bf   = (ushort_t*)(o_vpss + (long long)BT * DD);  // [16384,512] bf16 weights (dead after gemm_vpw_norm; o_vpss written in mega2)

    // 1) all normalizations in one dispatch
    prep_all<<<4096 + 2 * NE, 256, 0, stream>>>(
        key_soft, keys, vparams, ksn_bf, keys_n_bf, vp_n, vp_n_bf, vpnT_bf);

    // 2) kss (symmetric, 36x16 tiles) + ksh (512 tiles) in one dispatch
    mega_gemm<<<576 + 512, 256, 0, stream>>>(
        ksn_bf, o_kss, ksn_bf, keys_n_bf, o_ksh);

    // 3) softmax -> w_bf; argmax with margin-based fp64 refinement (wave/row)
    softmax_argmax<<<BT / 4, 256, 0, stream>>>(o_ksh, key_soft, keys, o_idx, w_bf);

    // 4) vparams_w gemm with fused normalize + bf16 + hard gather
    gemm_vpw_norm<<<BT / 64, 256, 0, stream>>>(
        w_bf, vpnT_bf, o_idx, vp_n, o_vpw, vpw_bf, o_vph);

    // 5) vpss (symmetric) + vpsh in one dispatch
    mega_gemm<<<576 + 512, 256, 0, stream>>>(
        vpw_bf, o_vpss, vpw_bf, vp_n_bf, o_vpsh);
}